// Round 5
// baseline (228.105 us; speedup 1.0000x reference)
//
#include <hip/hip_runtime.h>
#include <hip/hip_bf16.h>
#include <stdint.h>

typedef __bf16 v8bf __attribute__((ext_vector_type(8)));
typedef float  v4f  __attribute__((ext_vector_type(4)));
typedef unsigned short u16;

#define NTOK 16384
#define KDIM 1024

__device__ __forceinline__ u16 f2bf(float f) {
  uint32_t b = __builtin_bit_cast(uint32_t, f);
  b += 0x7FFFu + ((b >> 16) & 1u);
  return (u16)(b >> 16);
}

__device__ __forceinline__ void gl_lds16(const u16* g, u16* l) {
  __builtin_amdgcn_global_load_lds(
      (const __attribute__((address_space(1))) uint32_t*)g,
      (__attribute__((address_space(3))) uint32_t*)l,
      16, 0, 0);
}

__device__ __forceinline__ void bar() {
  __builtin_amdgcn_sched_barrier(0);
  __builtin_amdgcn_s_barrier();
  __builtin_amdgcn_sched_barrier(0);
}
#define LGKM0() do { asm volatile("s_waitcnt lgkmcnt(0)" ::: "memory"); \
                     __builtin_amdgcn_sched_barrier(0); } while (0)
#define VMW(n)  do { asm volatile("s_waitcnt vmcnt(" #n ")" ::: "memory"); \
                     __builtin_amdgcn_sched_barrier(0); } while (0)

// ---------------- fused fp32 -> bf16 convert for all three tensors -----
__global__ void cvt_all(const float* __restrict__ x, const float* __restrict__ wq,
                        const float* __restrict__ wp, u16* __restrict__ xo,
                        u16* __restrict__ wqo, u16* __restrict__ wpo) {
  size_t id = (size_t)blockIdx.x * 256 + threadIdx.x;
  const float* src; u16* dst;
  if (id < 2097152)      { src = x  + id * 8;              dst = xo  + id * 8; }
  else if (id < 2490368) { src = wq + (id - 2097152) * 8;  dst = wqo + (id - 2097152) * 8; }
  else                   { src = wp + (id - 2490368) * 8;  dst = wpo + (id - 2490368) * 8; }
  float4 a = *(const float4*)(src);
  float4 b = *(const float4*)(src + 4);
  union { u16 u[8]; uint4 v; } pk;
  pk.u[0]=f2bf(a.x); pk.u[1]=f2bf(a.y); pk.u[2]=f2bf(a.z); pk.u[3]=f2bf(a.w);
  pk.u[4]=f2bf(b.x); pk.u[5]=f2bf(b.y); pk.u[6]=f2bf(b.z); pk.u[7]=f2bf(b.w);
  *(uint4*)(dst) = pk.v;
}

// ---------------- C = A * B^T + bias ; 256x256 tile, BK=32 -------------
// v5: 4-slot LDS ring (128 KiB dynamic), prefetch distance 3 K-tiles.
// Tile t computes from slot t&3 (2 phases, 16-MFMA clusters, as v4).
// Tile t's phases stage tile t+3 into slot (t+3)&3 = (t-1)&3, which was
// fully consumed at tile t-1's last phase (reads drained by each wave's
// own LGKM0 before its MFMA, all waves fenced by the final bar).
// Outstanding loads (4 per tile: A@P_a, B@P_b): steady state 12 after
// P_b issue. One VMW(8) per K-tile forces the 4 oldest = tile t+1 landed
// (issued 6 phases earlier -> HBM latency fully hidden). Tail: t=NT-3 ->
// VMW(4), t=NT-2 -> VMW(0), t=NT-1 -> none.
// Prologue: stage tiles 0,1,2 (12 loads), VMW(8) -> tile 0 landed.
template<int NTOT, bool OUT_BF16>
__global__ __launch_bounds__(512, 1)
void gemm_bt(const u16* __restrict__ A, const u16* __restrict__ Bw,
             const float* __restrict__ bias, void* __restrict__ out) {
  constexpr int NM = NTOK / 256;
  constexpr int NN = NTOT / 256;
  constexpr int NWG = NM * NN;           // %8 == 0 for both GEMMs
  constexpr int NT = KDIM / 32;          // 32 K-tiles
  const int bid = blockIdx.x;
  const int swz = (bid & 7) * (NWG / 8) + (bid >> 3);   // bijective XCD swizzle
  const int bm = swz % NM, bn = swz / NM;

  extern __shared__ __align__(16) u16 smem[];  // 128 KiB
  u16* ldsA = smem;                            // [4][256*32]
  u16* ldsB = smem + 4 * 8192;                 // [4][256*32]

  const int tid = threadIdx.x, lane = tid & 63, w = tid >> 6;
  const int wr = w >> 2, wc = w & 3;

  v4f acc[8][4];
#pragma unroll
  for (int i = 0; i < 8; ++i)
#pragma unroll
    for (int j = 0; j < 4; ++j) acc[i][j] = v4f{0.f, 0.f, 0.f, 0.f};

  const u16* Ab = A  + (size_t)bm * 256 * KDIM;
  const u16* Bb = Bw + (size_t)bn * 256 * KDIM;

  // staging: thread covers chunks tid and tid+512 of a 256x32 tile (16KB).
  // LDS dest linear; global source carries the chunk XOR permutation.
  const size_t soff0 = (size_t)(tid >> 2) * KDIM
      + (size_t)((((tid & 3) ^ ((tid >> 2) & 3) ^ ((tid >> 4) & 3)) & 3) * 8);
  auto stageT = [&](u16* dst, const u16* src) {
    gl_lds16(src + soff0, dst + (size_t)tid * 8);
    gl_lds16(src + soff0 + (size_t)128 * KDIM, dst + (size_t)tid * 8 + 4096);
  };

  // frag reads: swizzled chunk folds to a per-lane constant
  const int cks = ((lane >> 4) ^ (lane & 3) ^ ((lane >> 2) & 3)) & 3;
  const int aoff = (wr * 128 + (lane & 15)) * 32 + cks * 8;
  const int boff = (wc * 64  + (lane & 15)) * 32 + cks * 8;

  // VMODE: 0 -> VMW(8), 1 -> VMW(4), 2 -> VMW(0), 3 -> none
#define TILE(ST, U, DO_STAGE, VMODE) do {                                     \
  const u16* La_ = ldsA + (ST) * 8192;                                        \
  const u16* Lb_ = ldsB + (ST) * 8192;                                        \
  v8bf af[4], bf4[4];                                                         \
  _Pragma("unroll") for (int f = 0; f < 4; ++f)                               \
    af[f] = *(const v8bf*)(La_ + aoff + f * 512);                             \
  _Pragma("unroll") for (int f = 0; f < 4; ++f)                               \
    bf4[f] = *(const v8bf*)(Lb_ + boff + f * 512);                            \
  if (DO_STAGE) stageT(ldsA + (((ST) + 3) & 3) * 8192,                        \
                       Ab + (size_t)(U) * 32);                                \
  bar(); LGKM0();                                                             \
  __builtin_amdgcn_s_setprio(1);                                              \
  _Pragma("unroll") for (int qi = 0; qi < 4; ++qi)                            \
  _Pragma("unroll") for (int qj = 0; qj < 4; ++qj)                            \
    acc[qi][qj] = __builtin_amdgcn_mfma_f32_16x16x32_bf16(                    \
        af[qi], bf4[qj], acc[qi][qj], 0, 0, 0);                               \
  __builtin_amdgcn_s_setprio(0);                                              \
  bar();                                                                      \
  _Pragma("unroll") for (int f = 0; f < 4; ++f)                               \
    af[f] = *(const v8bf*)(La_ + aoff + (f + 4) * 512);                       \
  if (DO_STAGE) stageT(ldsB + (((ST) + 3) & 3) * 8192,                        \
                       Bb + (size_t)(U) * 32);                                \
  bar(); LGKM0();                                                             \
  __builtin_amdgcn_s_setprio(1);                                              \
  _Pragma("unroll") for (int qi = 0; qi < 4; ++qi)                            \
  _Pragma("unroll") for (int qj = 0; qj < 4; ++qj)                            \
    acc[4 + qi][qj] = __builtin_amdgcn_mfma_f32_16x16x32_bf16(                \
        af[qi], bf4[qj], acc[4 + qi][qj], 0, 0, 0);                           \
  __builtin_amdgcn_s_setprio(0);                                              \
  if ((VMODE) == 0) { VMW(8); }                                               \
  else if ((VMODE) == 1) { VMW(4); }                                          \
  else if ((VMODE) == 2) { VMW(0); }                                          \
  bar();                                                                      \
} while (0)

  // prologue: tiles 0,1,2 into slots 0,1,2 (12 loads); force tile 0 landed.
  stageT(ldsA + 0,     Ab);        stageT(ldsB + 0,     Bb);
  stageT(ldsA + 8192,  Ab + 32);   stageT(ldsB + 8192,  Bb + 32);
  stageT(ldsA + 16384, Ab + 64);   stageT(ldsB + 16384, Bb + 64);
  VMW(8);
  bar();

  for (int j = 0; j < 7; ++j) {           // tiles 0..27: stage t+3 <= 30
    const int t0 = 4 * j;
    TILE(0, t0 + 3, 1, 0);
    TILE(1, t0 + 4, 1, 0);
    TILE(2, t0 + 5, 1, 0);
    TILE(3, t0 + 6, 1, 0);
  }
  // peeled tail: t = 28,29,30,31
  TILE(0, 31, 1, 0);                       // stage tile 31; force 29
  TILE(1, 0, 0, 1);                        // t=29: VMW(4) -> tile 30 landed
  TILE(2, 0, 0, 2);                        // t=30: VMW(0) -> tile 31 landed
  TILE(3, 0, 0, 3);                        // t=31: nothing outstanding
#undef TILE

  // C/D layout: col = lane&15, row = (lane>>4)*4 + j
  const int col0 = bn * 256 + wc * 64 + (lane & 15);
  const int row0 = bm * 256 + wr * 128 + ((lane >> 4) << 2);
#pragma unroll
  for (int mf = 0; mf < 8; ++mf) {
#pragma unroll
    for (int nf = 0; nf < 4; ++nf) {
      const int gc = col0 + nf * 16;
      const float bv = bias[gc];
#pragma unroll
      for (int j = 0; j < 4; ++j) {
        const size_t idx = (size_t)(row0 + mf * 16 + j) * NTOT + gc;
        const float v = acc[mf][nf][j] + bv;
        if constexpr (OUT_BF16) ((u16*)out)[idx] = f2bf(v);
        else                    ((float*)out)[idx] = v;
      }
    }
  }
}

// ---------------- per-token head-mix attention -------------------------
__global__ __launch_bounds__(256)
void attn_mix(const u16* __restrict__ qkv, u16* __restrict__ outp) {
  __shared__ __align__(16) u16 sq[4][3072];
  __shared__ float sp[4][16][16];
  const int tid = threadIdx.x, lane = tid & 63, w = tid >> 6;
  const size_t tok = (size_t)blockIdx.x * 4 + w;
  const u16* src = qkv + tok * 3072;
#pragma unroll
  for (int i = 0; i < 6; ++i) {
    int t = i * 64 + lane;
    int row = t >> 3;
    int c = (t & 7) ^ (row & 7);
    gl_lds16(src + row * 64 + c * 8, &sq[w][t * 8]);
  }
  __syncthreads();

  const int h = lane >> 2, gb = lane & 3;
  v8bf qv[8];
#pragma unroll
  for (int c = 0; c < 8; ++c)
    qv[c] = *(const v8bf*)&sq[w][h * 64 + ((c ^ (h & 7)) * 8)];

  float s[4];
#pragma unroll
  for (int g4 = 0; g4 < 4; ++g4) {
    const int g = gb * 4 + g4;
    float a = 0.f;
#pragma unroll
    for (int c = 0; c < 8; ++c) {
      v8bf kv = *(const v8bf*)&sq[w][1024 + g * 64 + ((c ^ (g & 7)) * 8)];
#pragma unroll
      for (int j = 0; j < 8; ++j) a += (float)qv[c][j] * (float)kv[j];
    }
    s[g4] = a * 0.125f;
  }
  float m = fmaxf(fmaxf(s[0], s[1]), fmaxf(s[2], s[3]));
  m = fmaxf(m, __shfl_xor(m, 1));
  m = fmaxf(m, __shfl_xor(m, 2));
  float p[4], sum = 0.f;
#pragma unroll
  for (int g4 = 0; g4 < 4; ++g4) { p[g4] = __expf(s[g4] - m); sum += p[g4]; }
  sum += __shfl_xor(sum, 1);
  sum += __shfl_xor(sum, 2);
  const float inv = 1.f / sum;
#pragma unroll
  for (int g4 = 0; g4 < 4; ++g4) sp[w][h][gb * 4 + g4] = p[g4] * inv;
  __syncthreads();

  float o[16];
#pragma unroll
  for (int j = 0; j < 16; ++j) o[j] = 0.f;
  const int db = gb;
#pragma unroll
  for (int g = 0; g < 16; ++g) {
    const float a = sp[w][h][g];
    v8bf v0 = *(const v8bf*)&sq[w][2048 + g * 64 + (((db * 2)     ^ (g & 7)) * 8)];
    v8bf v1 = *(const v8bf*)&sq[w][2048 + g * 64 + (((db * 2 + 1) ^ (g & 7)) * 8)];
#pragma unroll
    for (int j = 0; j < 8; ++j) { o[j] += a * (float)v0[j]; o[8 + j] += a * (float)v1[j]; }
  }
  union { u16 u[16]; uint4 v[2]; } ob;
#pragma unroll
  for (int j = 0; j < 16; ++j) ob.u[j] = f2bf(o[j]);
  u16* dst = outp + tok * 1024 + h * 64 + db * 16;
  *(uint4*)dst = ob.v[0];
  *((uint4*)dst + 1) = ob.v[1];
}

extern "C" void kernel_launch(void* const* d_in, const int* in_sizes, int n_in,
                              void* d_out, int out_size, void* d_ws, size_t ws_size,
                              hipStream_t stream) {
  const float* x      = (const float*)d_in[0];
  const float* w_qkv  = (const float*)d_in[1];
  const float* b_qkv  = (const float*)d_in[2];
  const float* w_proj = (const float*)d_in[3];
  const float* b_proj = (const float*)d_in[4];

  char* ws = (char*)d_ws;
  u16* x_bf    = (u16*)(ws);
  u16* wqkv_bf = (u16*)(ws + (size_t)33554432);
  u16* wp_bf   = (u16*)(ws + (size_t)39845888);
  u16* qkv_bf  = (u16*)(ws + (size_t)41943040);
  u16* at_bf   = (u16*)(ws + (size_t)142606336);

  // opt-in to 128 KiB dynamic LDS (host-side attribute, graph-capture safe)
  (void)hipFuncSetAttribute((const void*)&gemm_bt<3072, true>,
                            hipFuncAttributeMaxDynamicSharedMemorySize, 131072);
  (void)hipFuncSetAttribute((const void*)&gemm_bt<1024, false>,
                            hipFuncAttributeMaxDynamicSharedMemorySize, 131072);

  cvt_all<<<dim3(10240), dim3(256), 0, stream>>>(x, w_qkv, w_proj,
                                                 x_bf, wqkv_bf, wp_bf);

  gemm_bt<3072, true ><<<dim3(768), dim3(512), 131072, stream>>>(x_bf, wqkv_bf, b_qkv, qkv_bf);
  attn_mix<<<dim3(4096), dim3(256), 0, stream>>>(qkv_bf, at_bf);
  gemm_bt<1024, false><<<dim3(256), dim3(512), 131072, stream>>>(at_bf, wp_bf, b_proj, d_out);
}

// Round 7
// 221.515 us; speedup vs baseline: 1.0298x; 1.0298x over previous
//
#include <hip/hip_runtime.h>
#include <hip/hip_bf16.h>
#include <stdint.h>

typedef __bf16 v8bf __attribute__((ext_vector_type(8)));
typedef float  v4f  __attribute__((ext_vector_type(4)));
typedef unsigned short u16;

#define NTOK 16384
#define KDIM 1024

__device__ __forceinline__ u16 f2bf(float f) {
  uint32_t b = __builtin_bit_cast(uint32_t, f);
  b += 0x7FFFu + ((b >> 16) & 1u);
  return (u16)(b >> 16);
}

__device__ __forceinline__ void gl_lds16(const u16* g, u16* l) {
  __builtin_amdgcn_global_load_lds(
      (const __attribute__((address_space(1))) uint32_t*)g,
      (__attribute__((address_space(3))) uint32_t*)l,
      16, 0, 0);
}

__device__ __forceinline__ void bar() {
  __builtin_amdgcn_sched_barrier(0);
  __builtin_amdgcn_s_barrier();
  __builtin_amdgcn_sched_barrier(0);
}
#define LGKM0() do { asm volatile("s_waitcnt lgkmcnt(0)" ::: "memory"); \
                     __builtin_amdgcn_sched_barrier(0); } while (0)
#define VMW(n)  do { asm volatile("s_waitcnt vmcnt(" #n ")" ::: "memory"); \
                     __builtin_amdgcn_sched_barrier(0); } while (0)

// ---------------- fused fp32 -> bf16 convert for all three tensors -----
__global__ void cvt_all(const float* __restrict__ x, const float* __restrict__ wq,
                        const float* __restrict__ wp, u16* __restrict__ xo,
                        u16* __restrict__ wqo, u16* __restrict__ wpo) {
  size_t id = (size_t)blockIdx.x * 256 + threadIdx.x;
  const float* src; u16* dst;
  if (id < 2097152)      { src = x  + id * 8;              dst = xo  + id * 8; }
  else if (id < 2490368) { src = wq + (id - 2097152) * 8;  dst = wqo + (id - 2097152) * 8; }
  else                   { src = wp + (id - 2490368) * 8;  dst = wpo + (id - 2490368) * 8; }
  float4 a = *(const float4*)(src);
  float4 b = *(const float4*)(src + 4);
  union { u16 u[8]; uint4 v; } pk;
  pk.u[0]=f2bf(a.x); pk.u[1]=f2bf(a.y); pk.u[2]=f2bf(a.z); pk.u[3]=f2bf(a.w);
  pk.u[4]=f2bf(b.x); pk.u[5]=f2bf(b.y); pk.u[6]=f2bf(b.z); pk.u[7]=f2bf(b.w);
  *(uint4*)(dst) = pk.v;
}

// ---------------- C = A * B^T + bias ; 256x256 tile, BK=32 -------------
// v7 = v6 with the wait ledger FIXED: VMW precedes bar() (vmcnt is
// per-wave; "own-drain then barrier" is what makes a landing collective).
//
// Per tile t (frags FA,FB preloaded during tile t-1):
//   VMW(4); bar(t)  -> tile t+1's stage landed COLLECTIVELY
//                      (outstanding was 8: t+1 from body t-2, t+2 from t-1)
//   issue ds_read ab[0..3] = A rows 64..127 (slot t)       } overlaps
//   issue stage A(t+3),B(t+3) -> slot (t+3)&3 = (t-1)&3    }  cluster A
//   MFMA cluster A (16): acc[0..3] += FA x FB
//   lgkm0 (ab landed)
//   issue ds_read GA,GB = tile t+1 frags (slot (t+1)&3)    } overlaps cluster B
//   MFMA cluster B (16): acc[4..7] += ab x FB
//   lgkm0 (GA,GB landed -> become FA,FB of t+1)
// Hazards:
//   - ab read of slot t: forced by VMW(4)+bar at body t-1 (collective).
//   - GA/GB read of slot (t+1)&3: forced by VMW(4)+bar at body t.
//   - stage overwrite of slot (t-1)&3: every wave's reads of it were
//     LGKM0-drained before that wave reached bar(t); stage issued after.
// Tail: t=29 VMW(4), t=30 VMW(0), t=31 no wait/stage/next-reads.
template<int NTOT, bool OUT_BF16>
__global__ __launch_bounds__(512, 2)
void gemm_bt(const u16* __restrict__ A, const u16* __restrict__ Bw,
             const float* __restrict__ bias, void* __restrict__ out) {
  constexpr int NM = NTOK / 256;
  constexpr int NN = NTOT / 256;
  constexpr int NWG = NM * NN;           // %8 == 0 for both GEMMs
  constexpr int NT = KDIM / 32;          // 32 K-tiles
  const int bid = blockIdx.x;
  const int swz = (bid & 7) * (NWG / 8) + (bid >> 3);   // bijective XCD swizzle
  const int bm = swz % NM, bn = swz / NM;

  extern __shared__ __align__(16) u16 smem[];  // 128 KiB
  u16* ldsA = smem;                            // [4][256*32]
  u16* ldsB = smem + 4 * 8192;                 // [4][256*32]

  const int tid = threadIdx.x, lane = tid & 63, w = tid >> 6;
  const int wr = w >> 2, wc = w & 3;

  v4f acc[8][4];
#pragma unroll
  for (int i = 0; i < 8; ++i)
#pragma unroll
    for (int j = 0; j < 4; ++j) acc[i][j] = v4f{0.f, 0.f, 0.f, 0.f};

  const u16* Ab = A  + (size_t)bm * 256 * KDIM;
  const u16* Bb = Bw + (size_t)bn * 256 * KDIM;

  // staging: thread covers chunks tid and tid+512 of a 256x32 tile (16KB).
  const size_t soff0 = (size_t)(tid >> 2) * KDIM
      + (size_t)((((tid & 3) ^ ((tid >> 2) & 3) ^ ((tid >> 4) & 3)) & 3) * 8);
  auto stageT = [&](u16* dst, const u16* src) {
    gl_lds16(src + soff0, dst + (size_t)tid * 8);
    gl_lds16(src + soff0 + (size_t)128 * KDIM, dst + (size_t)tid * 8 + 4096);
  };

  // frag reads: swizzled chunk folds to a per-lane constant
  const int cks = ((lane >> 4) ^ (lane & 3) ^ ((lane >> 2) & 3)) & 3;
  const int aoff = (wr * 128 + (lane & 15)) * 32 + cks * 8;
  const int boff = (wc * 64  + (lane & 15)) * 32 + cks * 8;

  v8bf a0[4], b0[4], a1[4], b1[4];

  // VMODE: 0 -> VMW(4), 1 -> VMW(0), 2 -> none   (wait BEFORE bar)
#define TILE(T, FA, FB, GA, GB, DOSTAGE, VMODE, DONEXT) do {                  \
  const u16* La_c = ldsA + ((T) & 3) * 8192;                                  \
  const u16* La_n = ldsA + (((T) + 1) & 3) * 8192;                            \
  const u16* Lb_n = ldsB + (((T) + 1) & 3) * 8192;                            \
  if ((VMODE) == 0) { VMW(4); } else if ((VMODE) == 1) { VMW(0); }            \
  bar();                                                                      \
  v8bf ab[4];                                                                 \
  _Pragma("unroll") for (int f = 0; f < 4; ++f)                               \
    ab[f] = *(const v8bf*)(La_c + aoff + (f + 4) * 512);                      \
  if (DOSTAGE) {                                                              \
    stageT(ldsA + (((T) + 3) & 3) * 8192, Ab + (size_t)((T) + 3) * 32);       \
    stageT(ldsB + (((T) + 3) & 3) * 8192, Bb + (size_t)((T) + 3) * 32);       \
  }                                                                           \
  __builtin_amdgcn_s_setprio(1);                                              \
  _Pragma("unroll") for (int qi = 0; qi < 4; ++qi)                            \
  _Pragma("unroll") for (int qj = 0; qj < 4; ++qj)                            \
    acc[qi][qj] = __builtin_amdgcn_mfma_f32_16x16x32_bf16(                    \
        FA[qi], FB[qj], acc[qi][qj], 0, 0, 0);                                \
  __builtin_amdgcn_s_setprio(0);                                              \
  LGKM0();                                                                    \
  if (DONEXT) {                                                               \
    _Pragma("unroll") for (int f = 0; f < 4; ++f)                             \
      GA[f] = *(const v8bf*)(La_n + aoff + f * 512);                          \
    _Pragma("unroll") for (int f = 0; f < 4; ++f)                             \
      GB[f] = *(const v8bf*)(Lb_n + boff + f * 512);                          \
  }                                                                           \
  __builtin_amdgcn_s_setprio(1);                                              \
  _Pragma("unroll") for (int qi = 0; qi < 4; ++qi)                            \
  _Pragma("unroll") for (int qj = 0; qj < 4; ++qj)                            \
    acc[4 + qi][qj] = __builtin_amdgcn_mfma_f32_16x16x32_bf16(                \
        ab[qi], FB[qj], acc[4 + qi][qj], 0, 0, 0);                            \
  __builtin_amdgcn_s_setprio(0);                                              \
  LGKM0();                                                                    \
} while (0)

  // prologue: tiles 0,1,2 into slots 0,1,2 (12 loads); force tile 0; preload.
  stageT(ldsA + 0,     Ab);        stageT(ldsB + 0,     Bb);
  stageT(ldsA + 8192,  Ab + 32);   stageT(ldsB + 8192,  Bb + 32);
  stageT(ldsA + 16384, Ab + 64);   stageT(ldsB + 16384, Bb + 64);
  VMW(8);
  bar();
#pragma unroll
  for (int f = 0; f < 4; ++f) a0[f] = *(const v8bf*)(ldsA + aoff + f * 512);
#pragma unroll
  for (int f = 0; f < 4; ++f) b0[f] = *(const v8bf*)(ldsB + boff + f * 512);
  LGKM0();

  for (int j = 0; j < 14; ++j) {          // tiles 0..27, all full bodies
    const int t0 = 2 * j;
    TILE(t0,     a0, b0, a1, b1, 1, 0, 1);
    TILE(t0 + 1, a1, b1, a0, b0, 1, 0, 1);
  }
  TILE(28, a0, b0, a1, b1, 1, 0, 1);      // stage 31; VMW4 -> force 29
  TILE(29, a1, b1, a0, b0, 0, 0, 1);      // VMW4 -> force 30
  TILE(30, a0, b0, a1, b1, 0, 1, 1);      // VMW0 -> force 31
  TILE(31, a1, b1, a0, b0, 0, 2, 0);      // drain
#undef TILE

  // C/D layout: col = lane&15, row = (lane>>4)*4 + j
  const int col0 = bn * 256 + wc * 64 + (lane & 15);
  const int row0 = bm * 256 + wr * 128 + ((lane >> 4) << 2);
#pragma unroll
  for (int mf = 0; mf < 8; ++mf) {
#pragma unroll
    for (int nf = 0; nf < 4; ++nf) {
      const int gc = col0 + nf * 16;
      const float bv = bias[gc];
#pragma unroll
      for (int j = 0; j < 4; ++j) {
        const size_t idx = (size_t)(row0 + mf * 16 + j) * NTOT + gc;
        const float v = acc[mf][nf][j] + bv;
        if constexpr (OUT_BF16) ((u16*)out)[idx] = f2bf(v);
        else                    ((float*)out)[idx] = v;
      }
    }
  }
}

// ---------------- per-token head-mix attention -------------------------
__global__ __launch_bounds__(256)
void attn_mix(const u16* __restrict__ qkv, u16* __restrict__ outp) {
  __shared__ __align__(16) u16 sq[4][3072];
  __shared__ float sp[4][16][16];
  const int tid = threadIdx.x, lane = tid & 63, w = tid >> 6;
  const size_t tok = (size_t)blockIdx.x * 4 + w;
  const u16* src = qkv + tok * 3072;
#pragma unroll
  for (int i = 0; i < 6; ++i) {
    int t = i * 64 + lane;
    int row = t >> 3;
    int c = (t & 7) ^ (row & 7);
    gl_lds16(src + row * 64 + c * 8, &sq[w][t * 8]);
  }
  __syncthreads();

  const int h = lane >> 2, gb = lane & 3;
  v8bf qv[8];
#pragma unroll
  for (int c = 0; c < 8; ++c)
    qv[c] = *(const v8bf*)&sq[w][h * 64 + ((c ^ (h & 7)) * 8)];

  float s[4];
#pragma unroll
  for (int g4 = 0; g4 < 4; ++g4) {
    const int g = gb * 4 + g4;
    float a = 0.f;
#pragma unroll
    for (int c = 0; c < 8; ++c) {
      v8bf kv = *(const v8bf*)&sq[w][1024 + g * 64 + ((c ^ (g & 7)) * 8)];
#pragma unroll
      for (int j = 0; j < 8; ++j) a += (float)qv[c][j] * (float)kv[j];
    }
    s[g4] = a * 0.125f;
  }
  float m = fmaxf(fmaxf(s[0], s[1]), fmaxf(s[2], s[3]));
  m = fmaxf(m, __shfl_xor(m, 1));
  m = fmaxf(m, __shfl_xor(m, 2));
  float p[4], sum = 0.f;
#pragma unroll
  for (int g4 = 0; g4 < 4; ++g4) { p[g4] = __expf(s[g4] - m); sum += p[g4]; }
  sum += __shfl_xor(sum, 1);
  sum += __shfl_xor(sum, 2);
  const float inv = 1.f / sum;
#pragma unroll
  for (int g4 = 0; g4 < 4; ++g4) sp[w][h][gb * 4 + g4] = p[g4] * inv;
  __syncthreads();

  float o[16];
#pragma unroll
  for (int j = 0; j < 16; ++j) o[j] = 0.f;
  const int db = gb;
#pragma unroll
  for (int g = 0; g < 16; ++g) {
    const float a = sp[w][h][g];
    v8bf v0 = *(const v8bf*)&sq[w][2048 + g * 64 + (((db * 2)     ^ (g & 7)) * 8)];
    v8bf v1 = *(const v8bf*)&sq[w][2048 + g * 64 + (((db * 2 + 1) ^ (g & 7)) * 8)];
#pragma unroll
    for (int j = 0; j < 8; ++j) { o[j] += a * (float)v0[j]; o[8 + j] += a * (float)v1[j]; }
  }
  union { u16 u[16]; uint4 v[2]; } ob;
#pragma unroll
  for (int j = 0; j < 16; ++j) ob.u[j] = f2bf(o[j]);
  u16* dst = outp + tok * 1024 + h * 64 + db * 16;
  *(uint4*)dst = ob.v[0];
  *((uint4*)dst + 1) = ob.v[1];
}

extern "C" void kernel_launch(void* const* d_in, const int* in_sizes, int n_in,
                              void* d_out, int out_size, void* d_ws, size_t ws_size,
                              hipStream_t stream) {
  const float* x      = (const float*)d_in[0];
  const float* w_qkv  = (const float*)d_in[1];
  const float* b_qkv  = (const float*)d_in[2];
  const float* w_proj = (const float*)d_in[3];
  const float* b_proj = (const float*)d_in[4];

  char* ws = (char*)d_ws;
  u16* x_bf    = (u16*)(ws);
  u16* wqkv_bf = (u16*)(ws + (size_t)33554432);
  u16* wp_bf   = (u16*)(ws + (size_t)39845888);
  u16* qkv_bf  = (u16*)(ws + (size_t)41943040);
  u16* at_bf   = (u16*)(ws + (size_t)142606336);

  (void)hipFuncSetAttribute((const void*)&gemm_bt<3072, true>,
                            hipFuncAttributeMaxDynamicSharedMemorySize, 131072);
  (void)hipFuncSetAttribute((const void*)&gemm_bt<1024, false>,
                            hipFuncAttributeMaxDynamicSharedMemorySize, 131072);

  cvt_all<<<dim3(10240), dim3(256), 0, stream>>>(x, w_qkv, w_proj,
                                                 x_bf, wqkv_bf, wp_bf);

  gemm_bt<3072, true ><<<dim3(768), dim3(512), 131072, stream>>>(x_bf, wqkv_bf, b_qkv, qkv_bf);
  attn_mix<<<dim3(4096), dim3(256), 0, stream>>>(qkv_bf, at_bf);
  gemm_bt<1024, false><<<dim3(256), dim3(512), 131072, stream>>>(at_bf, wp_bf, b_proj, d_out);
}

// Round 8
// 216.391 us; speedup vs baseline: 1.0541x; 1.0237x over previous
//
#include <hip/hip_runtime.h>
#include <hip/hip_bf16.h>
#include <stdint.h>

typedef __bf16 v8bf __attribute__((ext_vector_type(8)));
typedef float  v4f  __attribute__((ext_vector_type(4)));
typedef unsigned short u16;

#define NTOK 16384
#define KDIM 1024

__device__ __forceinline__ u16 f2bf(float f) {
  uint32_t b = __builtin_bit_cast(uint32_t, f);
  b += 0x7FFFu + ((b >> 16) & 1u);
  return (u16)(b >> 16);
}

__device__ __forceinline__ void gl_lds16(const u16* g, u16* l) {
  __builtin_amdgcn_global_load_lds(
      (const __attribute__((address_space(1))) uint32_t*)g,
      (__attribute__((address_space(3))) uint32_t*)l,
      16, 0, 0);
}

__device__ __forceinline__ void bar() {
  __builtin_amdgcn_sched_barrier(0);
  __builtin_amdgcn_s_barrier();
  __builtin_amdgcn_sched_barrier(0);
}
#define LGKM0() do { asm volatile("s_waitcnt lgkmcnt(0)" ::: "memory"); \
                     __builtin_amdgcn_sched_barrier(0); } while (0)
#define VMW(n)  do { asm volatile("s_waitcnt vmcnt(" #n ")" ::: "memory"); \
                     __builtin_amdgcn_sched_barrier(0); } while (0)

// ---------------- fused fp32 -> bf16 convert for all three tensors -----
__global__ void cvt_all(const float* __restrict__ x, const float* __restrict__ wq,
                        const float* __restrict__ wp, u16* __restrict__ xo,
                        u16* __restrict__ wqo, u16* __restrict__ wpo) {
  size_t id = (size_t)blockIdx.x * 256 + threadIdx.x;
  const float* src; u16* dst;
  if (id < 2097152)      { src = x  + id * 8;              dst = xo  + id * 8; }
  else if (id < 2490368) { src = wq + (id - 2097152) * 8;  dst = wqo + (id - 2097152) * 8; }
  else                   { src = wp + (id - 2490368) * 8;  dst = wpo + (id - 2490368) * 8; }
  float4 a = *(const float4*)(src);
  float4 b = *(const float4*)(src + 4);
  union { u16 u[8]; uint4 v; } pk;
  pk.u[0]=f2bf(a.x); pk.u[1]=f2bf(a.y); pk.u[2]=f2bf(a.z); pk.u[3]=f2bf(a.w);
  pk.u[4]=f2bf(b.x); pk.u[5]=f2bf(b.y); pk.u[6]=f2bf(b.z); pk.u[7]=f2bf(b.w);
  *(uint4*)(dst) = pk.v;
}

// ---------------- C = A * B^T + bias ; 256x256 tile, BK=64 -------------
// v8: m201 8-phase template port. 8 waves (2M x 4N), per-wave C 128x64.
// LDS 128 KiB = 2 dbuf x {A-lo,A-hi,B-lo,B-hi} half-tiles (16 KB each,
// [128 rows][64 k] bf16, 128 B rows).
//
// Swizzle (G4, both-sides involution, rule 21): LDS(row, c_phys) holds
// global 16B-chunk c_phys ^ (row&7). gl_lds dest is LINEAR (tid*16B);
// the SOURCE global chunk is pre-swizzled; ds_read applies the same XOR,
// which folds to per-lane constants ck0/ck1 (row&7 == lane&7 for all frags).
// This kills the 16-way conflict of linear [*][64] reads (m201: +29-35%).
//
// Per K-tile t (4 phases; quadrants of the wave's 128x64 C):
//  P0 {rd A0(8),B0(4); stage A-hi(t+1); bar; lgkm0; 16 MFMA acc[0..3][0..1]; bar}
//  P1 {rd B1(4);       stage B-lo(t+1); bar; lgkm0; 16 MFMA acc[0..3][2..3]; bar}
//  P2 {rd A1(8)->Af;   stage B-hi(t+1); bar; lgkm0; 16 MFMA acc[4..7][2..3]; bar}
//  P3 {                stage A-lo(t+2) into SAME dbuf; bar;
//                      16 MFMA acc[4..7][0..1]; VMW(2); bar}
// Wait ledger (2 loads per half-tile per thread, in-order issue):
//  at t's P3, outstanding = [A-lo(t+1)@(t-1)P3, A-hi(t+1)@tP0, B-lo(t+1)@tP1,
//  B-hi(t+1)@tP2, A-lo(t+2)@tP3] = 10; VMW(2) forces 8 -> ALL of tile t+1
//  landed, A-lo(t+2) stays in flight (never drain to 0 mid-loop). bar makes
//  it collective; t+1's P0 ds_reads are safe.
// WAR: A-lo(t+2) overwrites A-lo(t), whose last ds_read drained at each
//  wave's P2 lgkm0, collectively fenced by P2's end bar < P3's stage issue.
//  All other stages target the OPPOSITE dbuf. B0 regs live P0->P3; A regs
//  reused at P2 (last MFMA use at P1, fenced by P1's cluster + compiler).
// Tail: t=14 -> no P3 stage, VMW(0); t=15 -> no stages, no vmcnt wait.
template<int NTOT, bool OUT_BF16>
__global__ __launch_bounds__(512, 2)
void gemm_bt(const u16* __restrict__ A, const u16* __restrict__ Bw,
             const float* __restrict__ bias, void* __restrict__ out) {
  constexpr int NM = NTOK / 256;
  constexpr int NN = NTOT / 256;
  constexpr int NWG = NM * NN;           // %8 == 0 for both GEMMs
  constexpr int NT = KDIM / 64;          // 16 K-tiles
  const int bid = blockIdx.x;
  const int swz = (bid & 7) * (NWG / 8) + (bid >> 3);   // bijective XCD swizzle
  const int bm = swz % NM, bn = swz / NM;

  extern __shared__ __align__(16) u16 smem[];  // 2 x 32768 elems = 128 KiB

  const int tid = threadIdx.x, lane = tid & 63, w = tid >> 6;
  const int wr = w >> 2, wc = w & 3;

  v4f acc[8][4];
#pragma unroll
  for (int i = 0; i < 8; ++i)
#pragma unroll
    for (int j = 0; j < 4; ++j) acc[i][j] = v4f{0.f, 0.f, 0.f, 0.f};

  const u16* Ab = A  + (size_t)bm * 256 * KDIM;
  const u16* Bb = Bw + (size_t)bn * 256 * KDIM;

  // staging: half-tile = 128 rows x 64 k. thread -> rows tid>>3 and +64,
  // chunk (tid&7) pre-swizzled by row&7. LDS dst linear.
  const int srow = tid >> 3;
  const int sc   = (tid & 7) ^ (srow & 7);
  const size_t soff = (size_t)srow * KDIM + (size_t)sc * 8;
  auto stageH = [&](int dstoff, const u16* src) {
    gl_lds16(src + soff, smem + dstoff + (size_t)tid * 8);
    gl_lds16(src + soff + (size_t)64 * KDIM, smem + dstoff + (size_t)tid * 8 + 4096);
  };

  // frag-read constants: global chunk wanted = s*4 + (lane>>4);
  // phys = wanted ^ (row&7) = wanted ^ (lane&7)  (frag rows == lane&15 mod 8)
  const int rA  = lane & 15;
  const int ck0 = (((lane >> 4) ^ (lane & 7)) << 3);        // elems
  const int ck1 = ((((lane >> 4) + 4) ^ (lane & 7)) << 3);
  const int ha = wr * 8192;                                  // A half base
  const int hb = 16384 + (wc >> 1) * 8192 + (wc & 1) * 64 * 64;  // B half+strip

  v8bf Af[4][2], B0[2][2], B1[2][2];

#define MM16(FI, GI, BF) do {                                                 \
  _Pragma("unroll") for (int f = 0; f < 4; ++f)                               \
  _Pragma("unroll") for (int g = 0; g < 2; ++g) {                             \
    acc[(FI)+f][(GI)+g] = __builtin_amdgcn_mfma_f32_16x16x32_bf16(            \
        Af[f][0], BF[g][0], acc[(FI)+f][(GI)+g], 0, 0, 0);                    \
    acc[(FI)+f][(GI)+g] = __builtin_amdgcn_mfma_f32_16x16x32_bf16(            \
        Af[f][1], BF[g][1], acc[(FI)+f][(GI)+g], 0, 0, 0);                    \
  }                                                                           \
} while (0)

  // VM: 2 steady, 0 -> t=14 (VMW(0), no P3 stage), -1 -> t=15 (no waits)
#define TILE(T, D, DN, ST, VM) do {                                           \
  /* ---- P0 ---- */                                                          \
  _Pragma("unroll") for (int f = 0; f < 4; ++f) {                             \
    Af[f][0] = *(const v8bf*)(smem + (D) + ha + (f*16 + rA)*64 + ck0);        \
    Af[f][1] = *(const v8bf*)(smem + (D) + ha + (f*16 + rA)*64 + ck1); }      \
  _Pragma("unroll") for (int g = 0; g < 2; ++g) {                             \
    B0[g][0] = *(const v8bf*)(smem + (D) + hb + (g*16 + rA)*64 + ck0);        \
    B0[g][1] = *(const v8bf*)(smem + (D) + hb + (g*16 + rA)*64 + ck1); }      \
  if (ST) stageH((DN) + 8192, Ab + (size_t)128*KDIM + (size_t)((T)+1)*64);    \
  bar(); LGKM0();                                                             \
  __builtin_amdgcn_s_setprio(1); MM16(0, 0, B0);                              \
  __builtin_amdgcn_s_setprio(0); bar();                                       \
  /* ---- P1 ---- */                                                          \
  _Pragma("unroll") for (int g = 0; g < 2; ++g) {                             \
    B1[g][0] = *(const v8bf*)(smem + (D) + hb + (32 + g*16 + rA)*64 + ck0);   \
    B1[g][1] = *(const v8bf*)(smem + (D) + hb + (32 + g*16 + rA)*64 + ck1); } \
  if (ST) stageH((DN) + 16384, Bb + (size_t)((T)+1)*64);                      \
  bar(); LGKM0();                                                             \
  __builtin_amdgcn_s_setprio(1); MM16(0, 2, B1);                              \
  __builtin_amdgcn_s_setprio(0); bar();                                       \
  /* ---- P2 ---- */                                                          \
  _Pragma("unroll") for (int f = 0; f < 4; ++f) {                             \
    Af[f][0] = *(const v8bf*)(smem + (D) + ha + (64 + f*16 + rA)*64 + ck0);   \
    Af[f][1] = *(const v8bf*)(smem + (D) + ha + (64 + f*16 + rA)*64 + ck1); } \
  if (ST) stageH((DN) + 24576, Bb + (size_t)128*KDIM + (size_t)((T)+1)*64);   \
  bar(); LGKM0();                                                             \
  __builtin_amdgcn_s_setprio(1); MM16(4, 2, B1);                              \
  __builtin_amdgcn_s_setprio(0); bar();                                       \
  /* ---- P3 ---- */                                                          \
  if ((VM) == 2) stageH((D) + 0, Ab + (size_t)((T)+2)*64);                    \
  bar();                                                                      \
  __builtin_amdgcn_s_setprio(1); MM16(4, 0, B0);                              \
  __builtin_amdgcn_s_setprio(0);                                              \
  if ((VM) == 2) { VMW(2); } else if ((VM) == 0) { VMW(0); }                  \
  bar();                                                                      \
} while (0)

  // prologue: tile0's 4 halves + A-lo(1) (10 loads); VMW(2) -> tile0 landed.
  stageH(0,     Ab);
  stageH(8192,  Ab + (size_t)128 * KDIM);
  stageH(16384, Bb);
  stageH(24576, Bb + (size_t)128 * KDIM);
  stageH(32768, Ab + 64);
  VMW(2);
  bar();

  for (int j = 0; j < 7; ++j) {          // tiles 0..13
    const int t0 = 2 * j;
    TILE(t0,     0,     32768, 1, 2);
    TILE(t0 + 1, 32768, 0,     1, 2);
  }
  TILE(14, 0,     32768, 1, 0);          // stages t+1=15 at P0-P2; VMW(0)
  TILE(15, 32768, 0,     0, -1);         // clean drain
#undef TILE
#undef MM16

  // C/D layout: col = lane&15, row = (lane>>4)*4 + j
  const int col0 = bn * 256 + wc * 64 + (lane & 15);
  const int row0 = bm * 256 + wr * 128 + ((lane >> 4) << 2);
#pragma unroll
  for (int mf = 0; mf < 8; ++mf) {
#pragma unroll
    for (int nf = 0; nf < 4; ++nf) {
      const int gc = col0 + nf * 16;
      const float bv = bias[gc];
#pragma unroll
      for (int j = 0; j < 4; ++j) {
        const size_t idx = (size_t)(row0 + mf * 16 + j) * NTOT + gc;
        const float v = acc[mf][nf][j] + bv;
        if constexpr (OUT_BF16) ((u16*)out)[idx] = f2bf(v);
        else                    ((float*)out)[idx] = v;
      }
    }
  }
}

// ---------------- per-token head-mix attention -------------------------
__global__ __launch_bounds__(256)
void attn_mix(const u16* __restrict__ qkv, u16* __restrict__ outp) {
  __shared__ __align__(16) u16 sq[4][3072];
  __shared__ float sp[4][16][16];
  const int tid = threadIdx.x, lane = tid & 63, w = tid >> 6;
  const size_t tok = (size_t)blockIdx.x * 4 + w;
  const u16* src = qkv + tok * 3072;
#pragma unroll
  for (int i = 0; i < 6; ++i) {
    int t = i * 64 + lane;
    int row = t >> 3;
    int c = (t & 7) ^ (row & 7);
    gl_lds16(src + row * 64 + c * 8, &sq[w][t * 8]);
  }
  __syncthreads();

  const int h = lane >> 2, gb = lane & 3;
  v8bf qv[8];
#pragma unroll
  for (int c = 0; c < 8; ++c)
    qv[c] = *(const v8bf*)&sq[w][h * 64 + ((c ^ (h & 7)) * 8)];

  float s[4];
#pragma unroll
  for (int g4 = 0; g4 < 4; ++g4) {
    const int g = gb * 4 + g4;
    float a = 0.f;
#pragma unroll
    for (int c = 0; c < 8; ++c) {
      v8bf kv = *(const v8bf*)&sq[w][1024 + g * 64 + ((c ^ (g & 7)) * 8)];
#pragma unroll
      for (int j = 0; j < 8; ++j) a += (float)qv[c][j] * (float)kv[j];
    }
    s[g4] = a * 0.125f;
  }
  float m = fmaxf(fmaxf(s[0], s[1]), fmaxf(s[2], s[3]));
  m = fmaxf(m, __shfl_xor(m, 1));
  m = fmaxf(m, __shfl_xor(m, 2));
  float p[4], sum = 0.f;
#pragma unroll
  for (int g4 = 0; g4 < 4; ++g4) { p[g4] = __expf(s[g4] - m); sum += p[g4]; }
  sum += __shfl_xor(sum, 1);
  sum += __shfl_xor(sum, 2);
  const float inv = 1.f / sum;
#pragma unroll
  for (int g4 = 0; g4 < 4; ++g4) sp[w][h][gb * 4 + g4] = p[g4] * inv;
  __syncthreads();

  float o[16];
#pragma unroll
  for (int j = 0; j < 16; ++j) o[j] = 0.f;
  const int db = gb;
#pragma unroll
  for (int g = 0; g < 16; ++g) {
    const float a = sp[w][h][g];
    v8bf v0 = *(const v8bf*)&sq[w][2048 + g * 64 + (((db * 2)     ^ (g & 7)) * 8)];
    v8bf v1 = *(const v8bf*)&sq[w][2048 + g * 64 + (((db * 2 + 1) ^ (g & 7)) * 8)];
#pragma unroll
    for (int j = 0; j < 8; ++j) { o[j] += a * (float)v0[j]; o[8 + j] += a * (float)v1[j]; }
  }
  union { u16 u[16]; uint4 v[2]; } ob;
#pragma unroll
  for (int j = 0; j < 16; ++j) ob.u[j] = f2bf(o[j]);
  u16* dst = outp + tok * 1024 + h * 64 + db * 16;
  *(uint4*)dst = ob.v[0];
  *((uint4*)dst + 1) = ob.v[1];
}

extern "C" void kernel_launch(void* const* d_in, const int* in_sizes, int n_in,
                              void* d_out, int out_size, void* d_ws, size_t ws_size,
                              hipStream_t stream) {
  const float* x      = (const float*)d_in[0];
  const float* w_qkv  = (const float*)d_in[1];
  const float* b_qkv  = (const float*)d_in[2];
  const float* w_proj = (const float*)d_in[3];
  const float* b_proj = (const float*)d_in[4];

  char* ws = (char*)d_ws;
  u16* x_bf    = (u16*)(ws);
  u16* wqkv_bf = (u16*)(ws + (size_t)33554432);
  u16* wp_bf   = (u16*)(ws + (size_t)39845888);
  u16* qkv_bf  = (u16*)(ws + (size_t)41943040);
  u16* at_bf   = (u16*)(ws + (size_t)142606336);

  (void)hipFuncSetAttribute((const void*)&gemm_bt<3072, true>,
                            hipFuncAttributeMaxDynamicSharedMemorySize, 131072);
  (void)hipFuncSetAttribute((const void*)&gemm_bt<1024, false>,
                            hipFuncAttributeMaxDynamicSharedMemorySize, 131072);

  cvt_all<<<dim3(10240), dim3(256), 0, stream>>>(x, w_qkv, w_proj,
                                                 x_bf, wqkv_bf, wp_bf);

  gemm_bt<3072, true ><<<dim3(768), dim3(512), 131072, stream>>>(x_bf, wqkv_bf, b_qkv, qkv_bf);
  attn_mix<<<dim3(4096), dim3(256), 0, stream>>>(qkv_bf, at_bf);
  gemm_bt<1024, false><<<dim3(256), dim3(512), 131072, stream>>>(at_bf, wp_bf, b_proj, d_out);
}

// Round 9
// 206.806 us; speedup vs baseline: 1.1030x; 1.0463x over previous
//
#include <hip/hip_runtime.h>
#include <hip/hip_bf16.h>
#include <stdint.h>

typedef __bf16 v8bf __attribute__((ext_vector_type(8)));
typedef float  v4f  __attribute__((ext_vector_type(4)));
typedef unsigned short u16;

#define NTOK 16384
#define KDIM 1024

__device__ __forceinline__ u16 f2bf(float f) {
  uint32_t b = __builtin_bit_cast(uint32_t, f);
  b += 0x7FFFu + ((b >> 16) & 1u);
  return (u16)(b >> 16);
}

__device__ __forceinline__ void gl_lds16(const u16* g, u16* l) {
  __builtin_amdgcn_global_load_lds(
      (const __attribute__((address_space(1))) uint32_t*)g,
      (__attribute__((address_space(3))) uint32_t*)l,
      16, 0, 0);
}

__device__ __forceinline__ void bar() {
  __builtin_amdgcn_sched_barrier(0);
  __builtin_amdgcn_s_barrier();
  __builtin_amdgcn_sched_barrier(0);
}
#define LGKM0() do { asm volatile("s_waitcnt lgkmcnt(0)" ::: "memory"); \
                     __builtin_amdgcn_sched_barrier(0); } while (0)
#define VMW(n)  do { asm volatile("s_waitcnt vmcnt(" #n ")" ::: "memory"); \
                     __builtin_amdgcn_sched_barrier(0); } while (0)

// ---------------- fused fp32 -> bf16 convert for all three tensors -----
__global__ void cvt_all(const float* __restrict__ x, const float* __restrict__ wq,
                        const float* __restrict__ wp, u16* __restrict__ xo,
                        u16* __restrict__ wqo, u16* __restrict__ wpo) {
  size_t id = (size_t)blockIdx.x * 256 + threadIdx.x;
  const float* src; u16* dst;
  if (id < 2097152)      { src = x  + id * 8;              dst = xo  + id * 8; }
  else if (id < 2490368) { src = wq + (id - 2097152) * 8;  dst = wqo + (id - 2097152) * 8; }
  else                   { src = wp + (id - 2490368) * 8;  dst = wpo + (id - 2490368) * 8; }
  float4 a = *(const float4*)(src);
  float4 b = *(const float4*)(src + 4);
  union { u16 u[8]; uint4 v; } pk;
  pk.u[0]=f2bf(a.x); pk.u[1]=f2bf(a.y); pk.u[2]=f2bf(a.z); pk.u[3]=f2bf(a.w);
  pk.u[4]=f2bf(b.x); pk.u[5]=f2bf(b.y); pk.u[6]=f2bf(b.z); pk.u[7]=f2bf(b.w);
  *(uint4*)(dst) = pk.v;
}

// ---------------- C = A * B^T + bias ; 256x256 tile, BK=64 -------------
// v9: cross-phase ds_read pipelining. Geometry as v8 (8 waves 2Mx4N,
// per-wave C 128x64, LDS 2 bufs x {A-lo,A-hi,B-lo,B-hi} halves of 16 KB).
// Buf D=(t&1) holds tile t (consumed + gradually overwritten by t+2's
// stages); buf DN holds tile t+1 (fully landed by t.P1's VMW(0)+bar).
//
// Phase = { [VMW] ; [stages] ; lgkm0 ; prio1 ; 16 MFMA ; prio0 ;
//           [post-reads for LATER phases] ; end-bar }.  4 bars/tile.
// With end-bars only, all waves always sit in the same phase-interval.
//
//  P0: lgkm0(drains t-1.P3 reads); Q(0,0) A0xB0
//  P1: VMW(0); stage B-lo(t+2)->D; lgkm0; Q(0,2) A0xB1;  read A1(t)<-D (8)
//  P2: stage B-hi(t+2)->D; lgkm0(A1); Q(4,2) A1xB1;      read B1(t+1)<-DN (4)
//  P3: stage A-lo,A-hi(t+2)->D; lgkm0; Q(4,0) A1xB0;     read A0,B0(t+1)<-DN (12)
// Register liveness (Af=A0 then A1; B0r; B1r — ping-pong free):
//  Af: used P0,P1 -> overwritten P1-post; used P2,P3 -> overwritten P3-post.
//  B0r: used P0,P3 -> overwritten P3-post. B1r: used P1,P2 -> overwritten P2-post.
// VMW(0)@t.P1 forces [B-lo(t+1)@t-1.P1, B-hi(t+1)@t-1.P2, A(t+1)x2@t-1.P3]
//  = 8 loads, ALL issued >=2 phases earlier (slack ~2500cyc > HBM 900) ->
//  drain-to-0 costs nothing; collectivity fence = t.P1 end-bar, before the
//  first DN reads at t.P2-post. 
// WAR ledger (writer's stage phase > reader's drain-lgkm0's phase end-bar):
//  B-lo(t+2)@t.P1 > B0(t) reads drained t.P0-lgkm0, fenced t.P0-end-bar ✓
//  B-hi(t+2)@t.P2 > B0(t)@t.P0 ✓, B1(t) drained t-1.P3-lgkm0/end-bar ✓
//  A(t+2)@t.P3   > A1(t) reads drained t.P2-lgkm0, fenced t.P2-end-bar ✓
//                > A0(t) drained t.P0-lgkm0 ✓
// Within-phase stage/read targets are disjoint regions (checked per phase).
// Tail: stages only while t+2<=15 (t<=13); t+1 post-reads while t<=14.
template<int NTOT, bool OUT_BF16>
__global__ __launch_bounds__(512, 2)
void gemm_bt(const u16* __restrict__ A, const u16* __restrict__ Bw,
             const float* __restrict__ bias, void* __restrict__ out) {
  constexpr int NM = NTOK / 256;
  constexpr int NN = NTOT / 256;
  constexpr int NWG = NM * NN;           // %8 == 0 for both GEMMs
  const int bid = blockIdx.x;
  const int swz = (bid & 7) * (NWG / 8) + (bid >> 3);   // bijective XCD swizzle
  const int bm = swz % NM, bn = swz / NM;

  extern __shared__ __align__(16) u16 smem[];  // 2 x 32768 elems = 128 KiB

  const int tid = threadIdx.x, lane = tid & 63, w = tid >> 6;
  const int wr = w >> 2, wc = w & 3;

  v4f acc[8][4];
#pragma unroll
  for (int i = 0; i < 8; ++i)
#pragma unroll
    for (int j = 0; j < 4; ++j) acc[i][j] = v4f{0.f, 0.f, 0.f, 0.f};

  const u16* Ab = A  + (size_t)bm * 256 * KDIM;
  const u16* Bb = Bw + (size_t)bn * 256 * KDIM;

  // staging: half-tile = 128 rows x 64 k; thread -> rows tid>>3, +64;
  // chunk (tid&7) pre-swizzled by row&7 (source-side of the involution).
  const int srow = tid >> 3;
  const int sc   = (tid & 7) ^ (srow & 7);
  const size_t soff = (size_t)srow * KDIM + (size_t)sc * 8;
  auto stageH = [&](int dstoff, const u16* src) {
    gl_lds16(src + soff, smem + dstoff + (size_t)tid * 8);
    gl_lds16(src + soff + (size_t)64 * KDIM, smem + dstoff + (size_t)tid * 8 + 4096);
  };

  // frag reads: read-side swizzle folds to per-lane constants
  const int rA  = lane & 15;
  const int ck0 = (((lane >> 4) ^ (lane & 7)) << 3);
  const int ck1 = ((((lane >> 4) + 4) ^ (lane & 7)) << 3);
  const int ha = wr * 8192;
  const int hb = 16384 + (wc >> 1) * 8192 + (wc & 1) * 64 * 64;

  v8bf Af[4][2], B0r[2][2], B1r[2][2];

#define RD_A(BUF, ROFF) do {                                                  \
  _Pragma("unroll") for (int f = 0; f < 4; ++f) {                             \
    Af[f][0] = *(const v8bf*)(smem + (BUF) + ha + ((ROFF)+f*16+rA)*64 + ck0); \
    Af[f][1] = *(const v8bf*)(smem + (BUF) + ha + ((ROFF)+f*16+rA)*64 + ck1);}\
} while (0)
#define RD_B(BUF, REG, ROFF) do {                                             \
  _Pragma("unroll") for (int g = 0; g < 2; ++g) {                             \
    REG[g][0] = *(const v8bf*)(smem + (BUF) + hb + ((ROFF)+g*16+rA)*64 + ck0);\
    REG[g][1] = *(const v8bf*)(smem + (BUF) + hb + ((ROFF)+g*16+rA)*64 + ck1);}\
} while (0)
#define MM16(FI, GI, BF) do {                                                 \
  __builtin_amdgcn_s_setprio(1);                                              \
  _Pragma("unroll") for (int f = 0; f < 4; ++f)                               \
  _Pragma("unroll") for (int g = 0; g < 2; ++g) {                             \
    acc[(FI)+f][(GI)+g] = __builtin_amdgcn_mfma_f32_16x16x32_bf16(            \
        Af[f][0], BF[g][0], acc[(FI)+f][(GI)+g], 0, 0, 0);                    \
    acc[(FI)+f][(GI)+g] = __builtin_amdgcn_mfma_f32_16x16x32_bf16(            \
        Af[f][1], BF[g][1], acc[(FI)+f][(GI)+g], 0, 0, 0);                    \
  }                                                                           \
  __builtin_amdgcn_s_setprio(0);                                              \
} while (0)

#define TILE(T, D, DN, ST, PR) do {                                           \
  /* P0 */                                                                    \
  LGKM0(); MM16(0, 0, B0r); bar();                                            \
  /* P1 */                                                                    \
  VMW(0);                                                                     \
  if (ST) stageH((D) + 16384, Bb + (size_t)((T)+2) * 64);                     \
  LGKM0(); MM16(0, 2, B1r);                                                   \
  RD_A((D), 64);                                                              \
  bar();                                                                      \
  /* P2 */                                                                    \
  if (ST) stageH((D) + 24576, Bb + (size_t)128*KDIM + (size_t)((T)+2) * 64);  \
  LGKM0(); MM16(4, 2, B1r);                                                   \
  if (PR) RD_B((DN), B1r, 32);                                                \
  bar();                                                                      \
  /* P3 */                                                                    \
  if (ST) { stageH((D) + 0,    Ab + (size_t)((T)+2) * 64);                    \
            stageH((D) + 8192, Ab + (size_t)128*KDIM + (size_t)((T)+2)*64); } \
  LGKM0(); MM16(4, 0, B0r);                                                   \
  if (PR) { RD_A((DN), 0); RD_B((DN), B0r, 0); }                              \
  bar();                                                                      \
} while (0)

  // prologue: tile0 (8 loads) then tile1 (8); VMW(8) forces tile0 only;
  // tile1 forced by t0.P1's VMW(0). Pre-read A0(0),B0(0),B1(0).
  stageH(0,     Ab);
  stageH(8192,  Ab + (size_t)128 * KDIM);
  stageH(16384, Bb);
  stageH(24576, Bb + (size_t)128 * KDIM);
  stageH(32768 + 16384, Bb + 64);
  stageH(32768 + 24576, Bb + (size_t)128 * KDIM + 64);
  stageH(32768 + 0,     Ab + 64);
  stageH(32768 + 8192,  Ab + (size_t)128 * KDIM + 64);
  VMW(8);
  bar();
  RD_A(0, 0);
  RD_B(0, B0r, 0);
  RD_B(0, B1r, 32);

  for (int j = 0; j < 7; ++j) {          // tiles 0..13: full bodies
    TILE(2 * j,     0,     32768, 1, 1);
    TILE(2 * j + 1, 32768, 0,     1, 1);
  }
  TILE(14, 0,     32768, 0, 1);
  TILE(15, 32768, 0,     0, 0);
#undef TILE
#undef MM16
#undef RD_A
#undef RD_B

  // C/D layout: col = lane&15, row = (lane>>4)*4 + j
  const int col0 = bn * 256 + wc * 64 + (lane & 15);
  const int row0 = bm * 256 + wr * 128 + ((lane >> 4) << 2);
#pragma unroll
  for (int mf = 0; mf < 8; ++mf) {
#pragma unroll
    for (int nf = 0; nf < 4; ++nf) {
      const int gc = col0 + nf * 16;
      const float bv = bias[gc];
#pragma unroll
      for (int j = 0; j < 4; ++j) {
        const size_t idx = (size_t)(row0 + mf * 16 + j) * NTOT + gc;
        const float v = acc[mf][nf][j] + bv;
        if constexpr (OUT_BF16) ((u16*)out)[idx] = f2bf(v);
        else                    ((float*)out)[idx] = v;
      }
    }
  }
}

// ---------------- per-token head-mix attention -------------------------
__global__ __launch_bounds__(256)
void attn_mix(const u16* __restrict__ qkv, u16* __restrict__ outp) {
  __shared__ __align__(16) u16 sq[4][3072];
  __shared__ float sp[4][16][16];
  const int tid = threadIdx.x, lane = tid & 63, w = tid >> 6;
  const size_t tok = (size_t)blockIdx.x * 4 + w;
  const u16* src = qkv + tok * 3072;
#pragma unroll
  for (int i = 0; i < 6; ++i) {
    int t = i * 64 + lane;
    int row = t >> 3;
    int c = (t & 7) ^ (row & 7);
    gl_lds16(src + row * 64 + c * 8, &sq[w][t * 8]);
  }
  __syncthreads();

  const int h = lane >> 2, gb = lane & 3;
  v8bf qv[8];
#pragma unroll
  for (int c = 0; c < 8; ++c)
    qv[c] = *(const v8bf*)&sq[w][h * 64 + ((c ^ (h & 7)) * 8)];

  float s[4];
#pragma unroll
  for (int g4 = 0; g4 < 4; ++g4) {
    const int g = gb * 4 + g4;
    float a = 0.f;
#pragma unroll
    for (int c = 0; c < 8; ++c) {
      v8bf kv = *(const v8bf*)&sq[w][1024 + g * 64 + ((c ^ (g & 7)) * 8)];
#pragma unroll
      for (int j = 0; j < 8; ++j) a += (float)qv[c][j] * (float)kv[j];
    }
    s[g4] = a * 0.125f;
  }
  float m = fmaxf(fmaxf(s[0], s[1]), fmaxf(s[2], s[3]));
  m = fmaxf(m, __shfl_xor(m, 1));
  m = fmaxf(m, __shfl_xor(m, 2));
  float p[4], sum = 0.f;
#pragma unroll
  for (int g4 = 0; g4 < 4; ++g4) { p[g4] = __expf(s[g4] - m); sum += p[g4]; }
  sum += __shfl_xor(sum, 1);
  sum += __shfl_xor(sum, 2);
  const float inv = 1.f / sum;
#pragma unroll
  for (int g4 = 0; g4 < 4; ++g4) sp[w][h][gb * 4 + g4] = p[g4] * inv;
  __syncthreads();

  float o[16];
#pragma unroll
  for (int j = 0; j < 16; ++j) o[j] = 0.f;
  const int db = gb;
#pragma unroll
  for (int g = 0; g < 16; ++g) {
    const float a = sp[w][h][g];
    v8bf v0 = *(const v8bf*)&sq[w][2048 + g * 64 + (((db * 2)     ^ (g & 7)) * 8)];
    v8bf v1 = *(const v8bf*)&sq[w][2048 + g * 64 + (((db * 2 + 1) ^ (g & 7)) * 8)];
#pragma unroll
    for (int j = 0; j < 8; ++j) { o[j] += a * (float)v0[j]; o[8 + j] += a * (float)v1[j]; }
  }
  union { u16 u[16]; uint4 v[2]; } ob;
#pragma unroll
  for (int j = 0; j < 16; ++j) ob.u[j] = f2bf(o[j]);
  u16* dst = outp + tok * 1024 + h * 64 + db * 16;
  *(uint4*)dst = ob.v[0];
  *((uint4*)dst + 1) = ob.v[1];
}

extern "C" void kernel_launch(void* const* d_in, const int* in_sizes, int n_in,
                              void* d_out, int out_size, void* d_ws, size_t ws_size,
                              hipStream_t stream) {
  const float* x      = (const float*)d_in[0];
  const float* w_qkv  = (const float*)d_in[1];
  const float* b_qkv  = (const float*)d_in[2];
  const float* w_proj = (const float*)d_in[3];
  const float* b_proj = (const float*)d_in[4];

  char* ws = (char*)d_ws;
  u16* x_bf    = (u16*)(ws);
  u16* wqkv_bf = (u16*)(ws + (size_t)33554432);
  u16* wp_bf   = (u16*)(ws + (size_t)39845888);
  u16* qkv_bf  = (u16*)(ws + (size_t)41943040);
  u16* at_bf   = (u16*)(ws + (size_t)142606336);

  (void)hipFuncSetAttribute((const void*)&gemm_bt<3072, true>,
                            hipFuncAttributeMaxDynamicSharedMemorySize, 131072);
  (void)hipFuncSetAttribute((const void*)&gemm_bt<1024, false>,
                            hipFuncAttributeMaxDynamicSharedMemorySize, 131072);

  cvt_all<<<dim3(10240), dim3(256), 0, stream>>>(x, w_qkv, w_proj,
                                                 x_bf, wqkv_bf, wp_bf);

  gemm_bt<3072, true ><<<dim3(768), dim3(512), 131072, stream>>>(x_bf, wqkv_bf, b_qkv, qkv_bf);
  attn_mix<<<dim3(4096), dim3(256), 0, stream>>>(qkv_bf, at_bf);
  gemm_bt<1024, false><<<dim3(256), dim3(512), 131072, stream>>>(at_bf, wp_bf, b_proj, d_out);
}

// Round 10
// 199.322 us; speedup vs baseline: 1.1444x; 1.0375x over previous
//
#include <hip/hip_runtime.h>
#include <hip/hip_bf16.h>
#include <stdint.h>

typedef __bf16 v8bf __attribute__((ext_vector_type(8)));
typedef float  v4f  __attribute__((ext_vector_type(4)));
typedef unsigned short u16;

#define NTOK 16384
#define KDIM 1024

__device__ __forceinline__ u16 f2bf(float f) {
  uint32_t b = __builtin_bit_cast(uint32_t, f);
  b += 0x7FFFu + ((b >> 16) & 1u);
  return (u16)(b >> 16);
}

__device__ __forceinline__ void gl_lds16(const u16* g, u16* l) {
  __builtin_amdgcn_global_load_lds(
      (const __attribute__((address_space(1))) uint32_t*)g,
      (__attribute__((address_space(3))) uint32_t*)l,
      16, 0, 0);
}

__device__ __forceinline__ void bar() {
  __builtin_amdgcn_sched_barrier(0);
  __builtin_amdgcn_s_barrier();
  __builtin_amdgcn_sched_barrier(0);
}
#define LGKM0() do { asm volatile("s_waitcnt lgkmcnt(0)" ::: "memory"); \
                     __builtin_amdgcn_sched_barrier(0); } while (0)
#define VMW(n)  do { asm volatile("s_waitcnt vmcnt(" #n ")" ::: "memory"); \
                     __builtin_amdgcn_sched_barrier(0); } while (0)

// ---------------- fused fp32 -> bf16 convert for all three tensors -----
__global__ void cvt_all(const float* __restrict__ x, const float* __restrict__ wq,
                        const float* __restrict__ wp, u16* __restrict__ xo,
                        u16* __restrict__ wqo, u16* __restrict__ wpo) {
  size_t id = (size_t)blockIdx.x * 256 + threadIdx.x;
  const float* src; u16* dst;
  if (id < 2097152)      { src = x  + id * 8;              dst = xo  + id * 8; }
  else if (id < 2490368) { src = wq + (id - 2097152) * 8;  dst = wqo + (id - 2097152) * 8; }
  else                   { src = wp + (id - 2490368) * 8;  dst = wpo + (id - 2490368) * 8; }
  float4 a = *(const float4*)(src);
  float4 b = *(const float4*)(src + 4);
  union { u16 u[8]; uint4 v; } pk;
  pk.u[0]=f2bf(a.x); pk.u[1]=f2bf(a.y); pk.u[2]=f2bf(a.z); pk.u[3]=f2bf(a.w);
  pk.u[4]=f2bf(b.x); pk.u[5]=f2bf(b.y); pk.u[6]=f2bf(b.z); pk.u[7]=f2bf(b.w);
  *(uint4*)(dst) = pk.v;
}

// ---------------- C = A * B^T + bias ; 256x256 tile, BK=64 -------------
// v10 = v9 K-loop (verified) + persistent blocks (ROUNDS output tiles per
// block, grid 256 = 1 block/CU) + supertile XCD map + pipelined round
// boundary {next-prologue loads; C-write stores; VMW(0); bar; pre-reads}.
// Map: xcd=bid&7 owns bm-rows [8*xcd, 8*xcd+8) x all bn. q=r*32+loc;
// bm=xcd*8+(q&7); bn=q>>3. Bijective (NM=64). Per-XCD per-round working
// set: A 4MB (~its L2) + B cols; whole x_bf (32MB) + w (6MB) fit L3.
// Boundary safety: round r's last frag reads are lgkm0-drained per wave and
// fenced by TILE(15)'s end-bar before the next-prologue stages are issued;
// VMW(0) drains loads (stores ack early at L2); bar makes landings
// collective before pre-reads. Store srcs (acc) are read at issue, so
// acc re-zero after issuing stores is safe.
template<int NTOT, bool OUT_BF16, int ROUNDS>
__global__ __launch_bounds__(512, 2)
void gemm_bt(const u16* __restrict__ A, const u16* __restrict__ Bw,
             const float* __restrict__ bias, void* __restrict__ out) {
  constexpr int NM = NTOK / 256;         // 64 = 8 XCDs x 8 rows
  const int bid = blockIdx.x;
  const int xcd = bid & 7, loc = bid >> 3;

  extern __shared__ __align__(16) u16 smem[];  // 2 x 32768 elems = 128 KiB

  const int tid = threadIdx.x, lane = tid & 63, w = tid >> 6;
  const int wr = w >> 2, wc = w & 3;

  v4f acc[8][4];
#pragma unroll
  for (int i = 0; i < 8; ++i)
#pragma unroll
    for (int j = 0; j < 4; ++j) acc[i][j] = v4f{0.f, 0.f, 0.f, 0.f};

  // staging geometry (source-side swizzle; LDS dest linear)
  const int srow = tid >> 3;
  const int sc   = (tid & 7) ^ (srow & 7);
  const size_t soff = (size_t)srow * KDIM + (size_t)sc * 8;
  const u16* Ab; const u16* Bb; int bm, bn;
  auto setbase = [&](int r) {
    int q = r * 32 + loc;
    bm = xcd * 8 + (q & 7);
    bn = q >> 3;
    Ab = A  + (size_t)bm * 256 * KDIM;
    Bb = Bw + (size_t)bn * 256 * KDIM;
  };
  auto stageH = [&](int dstoff, const u16* src) {
    gl_lds16(src + soff, smem + dstoff + (size_t)tid * 8);
    gl_lds16(src + soff + (size_t)64 * KDIM, smem + dstoff + (size_t)tid * 8 + 4096);
  };
  auto prolog = [&]() {   // tiles 0 (buf0) then 1 (buf1): 16 loads
    stageH(0,     Ab);
    stageH(8192,  Ab + (size_t)128 * KDIM);
    stageH(16384, Bb);
    stageH(24576, Bb + (size_t)128 * KDIM);
    stageH(32768 + 16384, Bb + 64);
    stageH(32768 + 24576, Bb + (size_t)128 * KDIM + 64);
    stageH(32768 + 0,     Ab + 64);
    stageH(32768 + 8192,  Ab + (size_t)128 * KDIM + 64);
  };

  // frag reads: read-side swizzle folds to per-lane constants
  const int rA  = lane & 15;
  const int ck0 = (((lane >> 4) ^ (lane & 7)) << 3);
  const int ck1 = ((((lane >> 4) + 4) ^ (lane & 7)) << 3);
  const int ha = wr * 8192;
  const int hb = 16384 + (wc >> 1) * 8192 + (wc & 1) * 64 * 64;

  v8bf Af[4][2], B0r[2][2], B1r[2][2];

#define RD_A(BUF, ROFF) do {                                                  \
  _Pragma("unroll") for (int f = 0; f < 4; ++f) {                             \
    Af[f][0] = *(const v8bf*)(smem + (BUF) + ha + ((ROFF)+f*16+rA)*64 + ck0); \
    Af[f][1] = *(const v8bf*)(smem + (BUF) + ha + ((ROFF)+f*16+rA)*64 + ck1);}\
} while (0)
#define RD_B(BUF, REG, ROFF) do {                                             \
  _Pragma("unroll") for (int g = 0; g < 2; ++g) {                             \
    REG[g][0] = *(const v8bf*)(smem + (BUF) + hb + ((ROFF)+g*16+rA)*64 + ck0);\
    REG[g][1] = *(const v8bf*)(smem + (BUF) + hb + ((ROFF)+g*16+rA)*64 + ck1);}\
} while (0)
#define MM16(FI, GI, BF) do {                                                 \
  __builtin_amdgcn_s_setprio(1);                                              \
  _Pragma("unroll") for (int f = 0; f < 4; ++f)                               \
  _Pragma("unroll") for (int g = 0; g < 2; ++g) {                             \
    acc[(FI)+f][(GI)+g] = __builtin_amdgcn_mfma_f32_16x16x32_bf16(            \
        Af[f][0], BF[g][0], acc[(FI)+f][(GI)+g], 0, 0, 0);                    \
    acc[(FI)+f][(GI)+g] = __builtin_amdgcn_mfma_f32_16x16x32_bf16(            \
        Af[f][1], BF[g][1], acc[(FI)+f][(GI)+g], 0, 0, 0);                    \
  }                                                                           \
  __builtin_amdgcn_s_setprio(0);                                              \
} while (0)

#define TILE(T, D, DN, ST, PR) do {                                           \
  /* P0 */                                                                    \
  LGKM0(); MM16(0, 0, B0r); bar();                                            \
  /* P1 */                                                                    \
  VMW(0);                                                                     \
  if (ST) stageH((D) + 16384, Bb + (size_t)((T)+2) * 64);                     \
  LGKM0(); MM16(0, 2, B1r);                                                   \
  RD_A((D), 64);                                                              \
  bar();                                                                      \
  /* P2 */                                                                    \
  if (ST) stageH((D) + 24576, Bb + (size_t)128*KDIM + (size_t)((T)+2) * 64);  \
  LGKM0(); MM16(4, 2, B1r);                                                   \
  if (PR) RD_B((DN), B1r, 32);                                                \
  bar();                                                                      \
  /* P3 */                                                                    \
  if (ST) { stageH((D) + 0,    Ab + (size_t)((T)+2) * 64);                    \
            stageH((D) + 8192, Ab + (size_t)128*KDIM + (size_t)((T)+2)*64); } \
  LGKM0(); MM16(4, 0, B0r);                                                   \
  if (PR) { RD_A((DN), 0); RD_B((DN), B0r, 0); }                              \
  bar();                                                                      \
} while (0)

  // initial prologue (round 0): VMW(8) forces tile0's 8, leaves tile1's 8.
  setbase(0);
  prolog();
  VMW(8);
  bar();
  RD_A(0, 0);
  RD_B(0, B0r, 0);
  RD_B(0, B1r, 32);

  for (int r = 0; r < ROUNDS; ++r) {
    for (int j = 0; j < 7; ++j) {
      TILE(2 * j,     0,     32768, 1, 1);
      TILE(2 * j + 1, 32768, 0,     1, 1);
    }
    TILE(14, 0,     32768, 0, 1);
    TILE(15, 32768, 0,     0, 0);

    const int bmw = bm, bnw = bn;
    if (r + 1 < ROUNDS) { setbase(r + 1); prolog(); }   // loads first

    // C-write (stores issue under the prologue loads)
    {
      const int col0 = bnw * 256 + wc * 64 + (lane & 15);
      const int row0 = bmw * 256 + wr * 128 + ((lane >> 4) << 2);
#pragma unroll
      for (int mf = 0; mf < 8; ++mf) {
#pragma unroll
        for (int nf = 0; nf < 4; ++nf) {
          const int gc = col0 + nf * 16;
          const float bv = bias[gc];
#pragma unroll
          for (int j = 0; j < 4; ++j) {
            const size_t idx = (size_t)(row0 + mf * 16 + j) * NTOT + gc;
            const float v = acc[mf][nf][j] + bv;
            if constexpr (OUT_BF16) ((u16*)out)[idx] = f2bf(v);
            else                    ((float*)out)[idx] = v;
          }
        }
      }
    }

    if (r + 1 < ROUNDS) {
#pragma unroll
      for (int i = 0; i < 8; ++i)
#pragma unroll
        for (int j = 0; j < 4; ++j) acc[i][j] = v4f{0.f, 0.f, 0.f, 0.f};
      VMW(0);          // drain prologue loads (stores ack early at L2)
      bar();
      RD_A(0, 0);
      RD_B(0, B0r, 0);
      RD_B(0, B1r, 32);
    }
  }
#undef TILE
#undef MM16
#undef RD_A
#undef RD_B
}

// ---------------- per-token head-mix attention -------------------------
__global__ __launch_bounds__(256)
void attn_mix(const u16* __restrict__ qkv, u16* __restrict__ outp) {
  __shared__ __align__(16) u16 sq[4][3072];
  __shared__ float sp[4][16][16];
  const int tid = threadIdx.x, lane = tid & 63, w = tid >> 6;
  const size_t tok = (size_t)blockIdx.x * 4 + w;
  const u16* src = qkv + tok * 3072;
#pragma unroll
  for (int i = 0; i < 6; ++i) {
    int t = i * 64 + lane;
    int row = t >> 3;
    int c = (t & 7) ^ (row & 7);
    gl_lds16(src + row * 64 + c * 8, &sq[w][t * 8]);
  }
  __syncthreads();

  const int h = lane >> 2, gb = lane & 3;
  v8bf qv[8];
#pragma unroll
  for (int c = 0; c < 8; ++c)
    qv[c] = *(const v8bf*)&sq[w][h * 64 + ((c ^ (h & 7)) * 8)];

  float s[4];
#pragma unroll
  for (int g4 = 0; g4 < 4; ++g4) {
    const int g = gb * 4 + g4;
    float a = 0.f;
#pragma unroll
    for (int c = 0; c < 8; ++c) {
      v8bf kv = *(const v8bf*)&sq[w][1024 + g * 64 + ((c ^ (g & 7)) * 8)];
#pragma unroll
      for (int j = 0; j < 8; ++j) a += (float)qv[c][j] * (float)kv[j];
    }
    s[g4] = a * 0.125f;
  }
  float m = fmaxf(fmaxf(s[0], s[1]), fmaxf(s[2], s[3]));
  m = fmaxf(m, __shfl_xor(m, 1));
  m = fmaxf(m, __shfl_xor(m, 2));
  float p[4], sum = 0.f;
#pragma unroll
  for (int g4 = 0; g4 < 4; ++g4) { p[g4] = __expf(s[g4] - m); sum += p[g4]; }
  sum += __shfl_xor(sum, 1);
  sum += __shfl_xor(sum, 2);
  const float inv = 1.f / sum;
#pragma unroll
  for (int g4 = 0; g4 < 4; ++g4) sp[w][h][gb * 4 + g4] = p[g4] * inv;
  __syncthreads();

  float o[16];
#pragma unroll
  for (int j = 0; j < 16; ++j) o[j] = 0.f;
  const int db = gb;
#pragma unroll
  for (int g = 0; g < 16; ++g) {
    const float a = sp[w][h][g];
    v8bf v0 = *(const v8bf*)&sq[w][2048 + g * 64 + (((db * 2)     ^ (g & 7)) * 8)];
    v8bf v1 = *(const v8bf*)&sq[w][2048 + g * 64 + (((db * 2 + 1) ^ (g & 7)) * 8)];
#pragma unroll
    for (int j = 0; j < 8; ++j) { o[j] += a * (float)v0[j]; o[8 + j] += a * (float)v1[j]; }
  }
  union { u16 u[16]; uint4 v[2]; } ob;
#pragma unroll
  for (int j = 0; j < 16; ++j) ob.u[j] = f2bf(o[j]);
  u16* dst = outp + tok * 1024 + h * 64 + db * 16;
  *(uint4*)dst = ob.v[0];
  *((uint4*)dst + 1) = ob.v[1];
}

extern "C" void kernel_launch(void* const* d_in, const int* in_sizes, int n_in,
                              void* d_out, int out_size, void* d_ws, size_t ws_size,
                              hipStream_t stream) {
  const float* x      = (const float*)d_in[0];
  const float* w_qkv  = (const float*)d_in[1];
  const float* b_qkv  = (const float*)d_in[2];
  const float* w_proj = (const float*)d_in[3];
  const float* b_proj = (const float*)d_in[4];

  char* ws = (char*)d_ws;
  u16* x_bf    = (u16*)(ws);
  u16* wqkv_bf = (u16*)(ws + (size_t)33554432);
  u16* wp_bf   = (u16*)(ws + (size_t)39845888);
  u16* qkv_bf  = (u16*)(ws + (size_t)41943040);
  u16* at_bf   = (u16*)(ws + (size_t)142606336);

  (void)hipFuncSetAttribute((const void*)&gemm_bt<3072, true, 3>,
                            hipFuncAttributeMaxDynamicSharedMemorySize, 131072);
  (void)hipFuncSetAttribute((const void*)&gemm_bt<1024, false, 1>,
                            hipFuncAttributeMaxDynamicSharedMemorySize, 131072);

  cvt_all<<<dim3(10240), dim3(256), 0, stream>>>(x, w_qkv, w_proj,
                                                 x_bf, wqkv_bf, wp_bf);

  gemm_bt<3072, true, 3><<<dim3(256), dim3(512), 131072, stream>>>(x_bf, wqkv_bf, b_qkv, qkv_bf);
  attn_mix<<<dim3(4096), dim3(256), 0, stream>>>(qkv_bf, at_bf);
  gemm_bt<1024, false, 1><<<dim3(256), dim3(512), 131072, stream>>>(at_bf, wp_bf, b_proj, d_out);
}